// Round 4
// baseline (750.804 us; speedup 1.0000x reference)
//
#include <hip/hip_runtime.h>
#include <hip/hip_bf16.h>
#include <stdint.h>

#define N_NODES 100000
#define DIM 256
#define HID 512
#define N_EDGES 1600000
#define NCHUNK 391                 // 391*256 = 100096 >= N_NODES
#define MTILES 782                 // ceil(100000/128)

using short8 = __attribute__((ext_vector_type(8))) short;
using f32x4  = __attribute__((ext_vector_type(4))) float;

__device__ __forceinline__ unsigned short f2bf(float f) {
    union { float f; unsigned u; } v; v.f = f;
    unsigned u = v.u;
    unsigned r = u + 0x7fffu + ((u >> 16) & 1u);   // RNE
    return (unsigned short)(r >> 16);
}
__device__ __forceinline__ float bf2f(unsigned short u) {
    union { unsigned u; float f; } v; v.u = ((unsigned)u) << 16; return v.f;
}
__device__ __forceinline__ void gload_lds16(const void* g, void* l) {
    __builtin_amdgcn_global_load_lds((const __attribute__((address_space(1))) void*)g,
                                     (__attribute__((address_space(3))) void*)l, 16, 0, 0);
}

// x fp32 -> bf16, 8 elems/thread
__global__ void x2bf(const float* __restrict__ x, unsigned short* __restrict__ xb) {
    long i = (long)blockIdx.x * blockDim.x + threadIdx.x;
    float4 u0 = ((const float4*)x)[i * 2];
    float4 u1 = ((const float4*)x)[i * 2 + 1];
    short8 o;
    o[0] = (short)f2bf(u0.x); o[1] = (short)f2bf(u0.y);
    o[2] = (short)f2bf(u0.z); o[3] = (short)f2bf(u0.w);
    o[4] = (short)f2bf(u1.x); o[5] = (short)f2bf(u1.y);
    o[6] = (short)f2bf(u1.z); o[7] = (short)f2bf(u1.w);
    ((short8*)xb)[i] = o;
}

// ---------------- counting-sort (CSR by dst) ----------------

__global__ void zero_counts(int* __restrict__ count) {
    count[blockIdx.x * 256 + threadIdx.x] = 0;
}

__global__ void histogram(const int* __restrict__ dst, int* __restrict__ count) {
    int e = blockIdx.x * 256 + threadIdx.x;
    atomicAdd(&count[dst[e]], 1);
}

__global__ void chunk_sums(const int* __restrict__ count, int* __restrict__ chunkSums) {
    __shared__ int sm[256];
    int t = threadIdx.x;
    sm[t] = count[blockIdx.x * 256 + t];
    __syncthreads();
    for (int s = 128; s > 0; s >>= 1) {
        if (t < s) sm[t] += sm[t + s];
        __syncthreads();
    }
    if (t == 0) chunkSums[blockIdx.x] = sm[0];
}

__global__ void scan_chunks(const int* __restrict__ chunkSums, int* __restrict__ chunkOff) {
    __shared__ int sm[512];
    int t = threadIdx.x;
    int v = (t < NCHUNK) ? chunkSums[t] : 0;
    sm[t] = v;
    __syncthreads();
    for (int off = 1; off < 512; off <<= 1) {
        int add = (t >= off) ? sm[t - off] : 0;
        __syncthreads();
        sm[t] += add;
        __syncthreads();
    }
    chunkOff[t] = sm[t] - v;   // exclusive
}

__global__ void scan_within(const int* __restrict__ count, const int* __restrict__ chunkOff,
                            int* __restrict__ start, int* __restrict__ cursor) {
    __shared__ int sm[256];
    int t = threadIdx.x;
    int gid = blockIdx.x * 256 + t;
    int v = count[gid];
    sm[t] = v;
    __syncthreads();
    for (int off = 1; off < 256; off <<= 1) {
        int add = (t >= off) ? sm[t - off] : 0;
        __syncthreads();
        sm[t] += add;
        __syncthreads();
    }
    int sv = sm[t] - v + chunkOff[blockIdx.x];
    start[gid] = sv;
    cursor[gid] = sv;
}

// 8 dst-range passes: active write window ~800 KB stays L2-resident, so each
// 64B line of sorted_src fills completely before its single writeback.
#define SP_BLOCKS 1250
#define SP_RANGE  12500   // N_NODES / 8
__global__ void scatter_pos(const int* __restrict__ src, const int* __restrict__ dst,
                            int* __restrict__ cursor, int* __restrict__ sorted_src) {
    int t0 = blockIdx.x * 256 + threadIdx.x;
    const int stride = SP_BLOCKS * 256;
    for (int p = 0; p < 8; ++p) {
        int lo = p * SP_RANGE, hi = lo + SP_RANGE;
        for (int e = t0; e < N_EDGES; e += stride) {
            int d = dst[e];
            if (d >= lo && d < hi) {
                int pos = atomicAdd(&cursor[d], 1);
                sorted_src[pos] = src[e];
            }
        }
    }
}

// one wave per node, bf16 rows: accb[n] = bf16( (1+eps)*x[n] + sum_neigh x[s] )
__global__ void gather_sum(const unsigned short* __restrict__ xb, const int* __restrict__ sorted_src,
                           const int* __restrict__ start, const int* __restrict__ count,
                           const float* __restrict__ eps, unsigned short* __restrict__ accb) {
    int lane = threadIdx.x & 63;
    int n = blockIdx.x * 4 + (threadIdx.x >> 6);
    if (n >= N_NODES) return;
    float s = 1.0f + eps[0];
    const ushort4* xr = (const ushort4*)(xb + (size_t)n * DIM);
    ushort4 v = xr[lane];
    float a0 = bf2f(v.x) * s, a1 = bf2f(v.y) * s, a2 = bf2f(v.z) * s, a3 = bf2f(v.w) * s;
    int base = start[n];
    int end = base + count[n];
    int j = base;
    for (; j + 4 <= end; j += 4) {
        int s0 = sorted_src[j], s1 = sorted_src[j + 1];
        int s2 = sorted_src[j + 2], s3 = sorted_src[j + 3];
        ushort4 v0 = ((const ushort4*)(xb + (size_t)s0 * DIM))[lane];
        ushort4 v1 = ((const ushort4*)(xb + (size_t)s1 * DIM))[lane];
        ushort4 v2 = ((const ushort4*)(xb + (size_t)s2 * DIM))[lane];
        ushort4 v3 = ((const ushort4*)(xb + (size_t)s3 * DIM))[lane];
        a0 += bf2f(v0.x) + bf2f(v1.x) + bf2f(v2.x) + bf2f(v3.x);
        a1 += bf2f(v0.y) + bf2f(v1.y) + bf2f(v2.y) + bf2f(v3.y);
        a2 += bf2f(v0.z) + bf2f(v1.z) + bf2f(v2.z) + bf2f(v3.z);
        a3 += bf2f(v0.w) + bf2f(v1.w) + bf2f(v2.w) + bf2f(v3.w);
    }
    for (; j < end; ++j) {
        int s0 = sorted_src[j];
        ushort4 v0 = ((const ushort4*)(xb + (size_t)s0 * DIM))[lane];
        a0 += bf2f(v0.x); a1 += bf2f(v0.y); a2 += bf2f(v0.z); a3 += bf2f(v0.w);
    }
    ushort4 o;
    o.x = f2bf(a0); o.y = f2bf(a1); o.z = f2bf(a2); o.w = f2bf(a3);
    ((ushort4*)(accb + (size_t)n * DIM))[lane] = o;
}

// ---------------- MLP ----------------

__global__ void prep_weights(const float* __restrict__ W1, const float* __restrict__ W2,
                             unsigned short* __restrict__ W1t, unsigned short* __restrict__ W2t) {
    int tid = blockIdx.x * blockDim.x + threadIdx.x;
    if (tid < DIM * HID) {
        int n = tid >> 8, k = tid & 255;
        W1t[tid] = f2bf(W1[k * HID + n]);
    } else {
        int j = tid - DIM * HID;
        int n = j >> 9, k = j & 511;
        W2t[j] = f2bf(W2[k * DIM + n]);
    }
}

// 128x128 tile, 4 waves (2x2), each 64x64 via 4x4 of 16x16x32 bf16 MFMA.
// STATS variant (GEMM2): bf16 out + per-block column sum/sumsq -> partial[mtile][512].
template<int K, int NOUT, bool RELU_BF16_OUT, bool STATS>
__global__ __launch_bounds__(256) void gemm128(const unsigned short* __restrict__ A,
        const unsigned short* __restrict__ Bt, const float* __restrict__ bias,
        void* __restrict__ Cout, float* __restrict__ partial, int M) {
    __shared__ unsigned short As[128 * 32];   // 8 KB, row stride 64 B
    __shared__ unsigned short Bs[128 * 32];
    __shared__ float csum[128], csq[128];
    constexpr int NT = NOUT / 128;
    int mtile = blockIdx.x / NT;
    int ntile = blockIdx.x % NT;
    int mbase = mtile * 128, nbase = ntile * 128;
    int t = threadIdx.x;
    int lane = t & 63, wid = t >> 6;
    int wm = (wid & 1) * 64, wn = (wid >> 1) * 64;
    int lo = lane & 15, quad = lane >> 4;

    if (STATS && t < 128) { csum[t] = 0.f; csq[t] = 0.f; }

    int s0 = t, s1 = t + 256;
    int r0 = s0 >> 2, c0 = (s0 & 3) ^ ((r0 >> 1) & 3);
    int r1 = s1 >> 2, c1 = (s1 & 3) ^ ((r1 >> 1) & 3);
    int gmA0 = mbase + r0; if (gmA0 >= M) gmA0 = M - 1;
    int gmA1 = mbase + r1; if (gmA1 >= M) gmA1 = M - 1;
    const unsigned short* gA0 = A + (size_t)gmA0 * K + c0 * 8;
    const unsigned short* gA1 = A + (size_t)gmA1 * K + c1 * 8;
    const unsigned short* gB0 = Bt + (size_t)(nbase + r0) * K + c0 * 8;
    const unsigned short* gB1 = Bt + (size_t)(nbase + r1) * K + c1 * 8;
    char* lA0 = (char*)As + wid * 1024;
    char* lA1 = (char*)As + 4096 + wid * 1024;
    char* lB0 = (char*)Bs + wid * 1024;
    char* lB1 = (char*)Bs + 4096 + wid * 1024;

    int offA[4], offB[4];
    #pragma unroll
    for (int i = 0; i < 4; ++i) {
        int ra = wm + i * 16 + lo;
        offA[i] = ra * 64 + ((quad ^ ((ra >> 1) & 3)) * 16);
        int rb = wn + i * 16 + lo;
        offB[i] = rb * 64 + ((quad ^ ((rb >> 1) & 3)) * 16);
    }

    f32x4 acc[4][4] = {};
    for (int kt = 0; kt < K / 32; ++kt) {
        if (kt) __syncthreads();
        int ko = kt * 32;
        gload_lds16(gA0 + ko, lA0);
        gload_lds16(gA1 + ko, lA1);
        gload_lds16(gB0 + ko, lB0);
        gload_lds16(gB1 + ko, lB1);
        __syncthreads();
        short8 a[4], b[4];
        #pragma unroll
        for (int i = 0; i < 4; ++i) {
            a[i] = *(const short8*)((const char*)As + offA[i]);
            b[i] = *(const short8*)((const char*)Bs + offB[i]);
        }
        #pragma unroll
        for (int mi = 0; mi < 4; ++mi)
            #pragma unroll
            for (int ni = 0; ni < 4; ++ni)
                acc[mi][ni] = __builtin_amdgcn_mfma_f32_16x16x32_bf16(a[mi], b[ni], acc[mi][ni], 0, 0, 0);
    }
    // epilogue: D layout col=lane&15, row=quad*4+reg
    #pragma unroll
    for (int ni = 0; ni < 4; ++ni) {
        int col = nbase + wn + ni * 16 + lo;
        float bcol = bias[col];
        float ssum = 0.f, ssq = 0.f;
        #pragma unroll
        for (int mi = 0; mi < 4; ++mi)
            #pragma unroll
            for (int r = 0; r < 4; ++r) {
                int row = mbase + wm + mi * 16 + quad * 4 + r;
                if (row < M) {
                    float v = acc[mi][ni][r] + bcol;
                    if constexpr (RELU_BF16_OUT) {
                        v = fmaxf(v, 0.0f);
                        ((unsigned short*)Cout)[(size_t)row * NOUT + col] = f2bf(v);
                    } else if constexpr (STATS) {
                        ((unsigned short*)Cout)[(size_t)row * NOUT + col] = f2bf(v);
                        ssum += v; ssq += v * v;
                    } else {
                        ((float*)Cout)[(size_t)row * NOUT + col] = v;
                    }
                }
            }
        if constexpr (STATS) {
            ssum += __shfl_xor(ssum, 16); ssum += __shfl_xor(ssum, 32);
            ssq  += __shfl_xor(ssq, 16);  ssq  += __shfl_xor(ssq, 32);
            if (quad == 0) {
                atomicAdd(&csum[wn + ni * 16 + lo], ssum);
                atomicAdd(&csq[wn + ni * 16 + lo], ssq);
            }
        }
    }
    if constexpr (STATS) {
        __syncthreads();
        if (t < 128) {
            partial[(size_t)mtile * 512 + nbase + t] = csum[t];
            partial[(size_t)mtile * 512 + 256 + nbase + t] = csq[t];
        }
    }
}

// ---------------- BatchNorm ----------------

__global__ void col_stats2(const float* __restrict__ partial, const float* __restrict__ gamma,
                           const float* __restrict__ beta, float* __restrict__ sc) {
    int t = threadIdx.x;
    float s = 0.f, q = 0.f;
    for (int m = 0; m < MTILES; ++m) {
        s += partial[(size_t)m * 512 + t];
        q += partial[(size_t)m * 512 + 256 + t];
    }
    float mean = s * (1.0f / (float)N_NODES);
    float var = q * (1.0f / (float)N_NODES) - mean * mean;
    float inv = rsqrtf(var + 1e-5f);
    float scale = gamma[t] * inv;
    sc[t] = scale;
    sc[256 + t] = beta[t] - mean * scale;
}

// read bf16 h2, write fp32 out; 8 elems/thread
__global__ void bn_apply(const unsigned short* __restrict__ h2b, const float* __restrict__ sc,
                         float* __restrict__ out) {
    long i = (long)blockIdx.x * blockDim.x + threadIdx.x;
    int c = (int)((i * 8) & (DIM - 1));
    short8 v = ((const short8*)h2b)[i];
    float4 sc0 = *(const float4*)(sc + c);
    float4 sc1 = *(const float4*)(sc + c + 4);
    float4 sh0 = *(const float4*)(sc + 256 + c);
    float4 sh1 = *(const float4*)(sc + 256 + c + 4);
    float4 o0, o1;
    o0.x = bf2f((unsigned short)v[0]) * sc0.x + sh0.x;
    o0.y = bf2f((unsigned short)v[1]) * sc0.y + sh0.y;
    o0.z = bf2f((unsigned short)v[2]) * sc0.z + sh0.z;
    o0.w = bf2f((unsigned short)v[3]) * sc0.w + sh0.w;
    o1.x = bf2f((unsigned short)v[4]) * sc1.x + sh1.x;
    o1.y = bf2f((unsigned short)v[5]) * sc1.y + sh1.y;
    o1.z = bf2f((unsigned short)v[6]) * sc1.z + sh1.z;
    o1.w = bf2f((unsigned short)v[7]) * sc1.w + sh1.w;
    ((float4*)out)[i * 2] = o0;
    ((float4*)out)[i * 2 + 1] = o1;
}

extern "C" void kernel_launch(void* const* d_in, const int* in_sizes, int n_in,
                              void* d_out, int out_size, void* d_ws, size_t ws_size,
                              hipStream_t stream) {
    const float* x     = (const float*)d_in[0];
    const int*   src   = (const int*)d_in[1];
    const int*   dst   = (const int*)d_in[2];
    const float* eps   = (const float*)d_in[3];
    const float* W1    = (const float*)d_in[4];
    const float* b1    = (const float*)d_in[5];
    const float* W2    = (const float*)d_in[6];
    const float* b2    = (const float*)d_in[7];
    const float* gamma = (const float*)d_in[8];
    const float* beta  = (const float*)d_in[9];

    char* ws = (char*)d_ws;
    // phase 1: xb @0 (51.2MB), accb @51.2MB (51.2MB)
    // phase 2 (GEMM2+): partial @0 (1.6MB, xb dead), h2b @51.2MB (accb dead)
    unsigned short* xb      = (unsigned short*)ws;
    float*          partial = (float*)ws;
    unsigned short* accb    = (unsigned short*)(ws + 51200000);
    unsigned short* h2b     = (unsigned short*)(ws + 51200000);
    unsigned short* W1t     = (unsigned short*)(ws + 102400000);  // 262,144 B
    unsigned short* W2t     = (unsigned short*)(ws + 102662144);  // 262,144 B
    float*          sc      = (float*)(ws + 102924288);           // 2,048 B

    // d_out phases: [sort scratch] -> [tbuf bf16 N x 512] -> [final out]
    char* ob = (char*)d_out;
    int* count      = (int*)ob;                    // 400,384 B
    int* start      = (int*)(ob + 400384);         // 400,384 B
    int* cursor     = (int*)(ob + 800768);         // 400,384 B
    int* chunkSums  = (int*)(ob + 1201152);        // 2,048 B
    int* chunkOff   = (int*)(ob + 1203200);        // 2,048 B
    int* sorted_src = (int*)(ob + 1205248);        // 6,400,000 B
    unsigned short* tbuf = (unsigned short*)d_out;
    float*          out  = (float*)d_out;

    hipLaunchKernelGGL(x2bf, dim3(12500), dim3(256), 0, stream, x, xb);
    hipLaunchKernelGGL(prep_weights, dim3(1024), dim3(256), 0, stream, W1, W2, W1t, W2t);
    hipLaunchKernelGGL(zero_counts, dim3(NCHUNK), dim3(256), 0, stream, count);
    hipLaunchKernelGGL(histogram, dim3(N_EDGES / 256), dim3(256), 0, stream, dst, count);
    hipLaunchKernelGGL(chunk_sums, dim3(NCHUNK), dim3(256), 0, stream, count, chunkSums);
    hipLaunchKernelGGL(scan_chunks, dim3(1), dim3(512), 0, stream, chunkSums, chunkOff);
    hipLaunchKernelGGL(scan_within, dim3(NCHUNK), dim3(256), 0, stream, count, chunkOff, start, cursor);
    hipLaunchKernelGGL(scatter_pos, dim3(SP_BLOCKS), dim3(256), 0, stream, src, dst, cursor, sorted_src);
    hipLaunchKernelGGL(gather_sum, dim3(25000), dim3(256), 0, stream,
                       xb, sorted_src, start, count, eps, accb);
    hipLaunchKernelGGL((gemm128<256, 512, true, false>), dim3(MTILES * 4), dim3(256), 0, stream,
                       accb, W1t, b1, (void*)tbuf, (float*)nullptr, N_NODES);
    hipLaunchKernelGGL((gemm128<512, 256, false, true>), dim3(MTILES * 2), dim3(256), 0, stream,
                       tbuf, W2t, b2, (void*)h2b, partial, N_NODES);
    hipLaunchKernelGGL(col_stats2, dim3(1), dim3(256), 0, stream, partial, gamma, beta, sc);
    hipLaunchKernelGGL(bn_apply, dim3(12500), dim3(256), 0, stream, h2b, sc, out);
}